// Round 2
// baseline (777.436 us; speedup 1.0000x reference)
//
#include <hip/hip_runtime.h>

#define BB 8
#define CC 512
#define NH 8
#define HD 64
#define HH 96
#define WW 96
#define AMP 3
#define KS 7
#define TH 16
#define TW 32
#define HALO_H (TH + 2*AMP)   // 22
#define HALO_W (TW + 2*AMP)   // 38
#define LDSW 41               // padded stride: 41 words -> <=2-way bank alias
#define DCH 8                 // d-planes staged per chunk

__global__ __launch_bounds__(256) void mov_kernel(const float* __restrict__ q,
                                                  const float* __restrict__ k,
                                                  float* __restrict__ out) {
    const int tid = threadIdx.x;          // 0..255
    const int tx  = tid & 15;             // 0..15  (w pairs)
    const int ty  = tid >> 4;             // 0..15  (h rows)
    const int tile = blockIdx.x;          // 0..17
    const int tw_i = tile % (WW / TW);    // 0..2
    const int th_i = tile / (WW / TW);    // 0..5
    const int n = blockIdx.y;
    const int b = blockIdx.z;
    const int h0 = th_i * TH;
    const int w0 = tw_i * TW;

    __shared__ float lk[DCH][HALO_H][LDSW];

    const int h = h0 + ty;
    const int w = w0 + 2 * tx;

    float acc0[KS * KS], acc1[KS * KS];
#pragma unroll
    for (int o = 0; o < KS * KS; ++o) { acc0[o] = 0.f; acc1[o] = 0.f; }

    const float scale = 0.125f;           // 64^-0.5
    const size_t plane = (size_t)HH * WW; // 9216
    const float* qbase = q + ((size_t)b * CC + n) * plane + (size_t)h * WW + w;
    const float* kbase = k + ((size_t)b * CC + n) * plane;

    for (int d0 = 0; d0 < HD; d0 += DCH) {
        __syncthreads();
        // ---- stage k halo for DCH planes ----
        for (int dd = 0; dd < DCH; ++dd) {
            const float* kp = kbase + (size_t)(d0 + dd) * NH * plane;
            for (int e = tid; e < HALO_H * HALO_W; e += 256) {
                int r  = e / HALO_W;
                int cc = e - r * HALO_W;
                int y = h0 + r - AMP;
                int x = w0 + cc - AMP;
                float v = 0.f;
                if ((unsigned)y < HH && (unsigned)x < WW)
                    v = kp[(size_t)y * WW + x];
                lk[dd][r][cc] = v;
            }
        }
        __syncthreads();
        // ---- accumulate 49 dots for the 2 pixels ----
#pragma unroll
        for (int dd = 0; dd < DCH; ++dd) {
            const float* qp = qbase + (size_t)(d0 + dd) * NH * plane;
            float q0 = qp[0] * scale;
            float q1 = qp[1] * scale;
#pragma unroll
            for (int i = 0; i < KS; ++i) {
                float kv[8];
#pragma unroll
                for (int t = 0; t < 8; ++t)
                    kv[t] = lk[dd][ty + i][2 * tx + t];
#pragma unroll
                for (int j = 0; j < KS; ++j) {
                    acc0[i * KS + j] += q0 * kv[j];
                    acc1[i * KS + j] += q1 * kv[j + 1];
                }
            }
        }
    }

    // ---- mask invalid offsets (reference: -1000 -> exp underflows to 0) ----
#pragma unroll
    for (int i = 0; i < KS; ++i) {
        bool vi = ((unsigned)(h + i - AMP) < HH);
#pragma unroll
        for (int j = 0; j < KS; ++j) {
            bool v0 = vi && ((unsigned)(w + j - AMP) < WW);
            bool v1 = vi && ((unsigned)(w + 1 + j - AMP) < WW);
            if (!v0) acc0[i * KS + j] = -1e30f;
            if (!v1) acc1[i * KS + j] = -1e30f;
        }
    }

    // ---- softmax over 49 offsets + expectation of (di, dj) ----
    float m0 = -1e30f, m1 = -1e30f;
#pragma unroll
    for (int o = 0; o < KS * KS; ++o) {
        m0 = fmaxf(m0, acc0[o]);
        m1 = fmaxf(m1, acc1[o]);
    }
    float l0 = 0.f, di0 = 0.f, dj0 = 0.f;
    float l1 = 0.f, di1 = 0.f, dj1 = 0.f;
#pragma unroll
    for (int i = 0; i < KS; ++i) {
#pragma unroll
        for (int j = 0; j < KS; ++j) {
            float e0 = __expf(acc0[i * KS + j] - m0);
            float e1 = __expf(acc1[i * KS + j] - m1);
            l0 += e0; l1 += e1;
            di0 += e0 * (float)(i - AMP);
            di1 += e1 * (float)(i - AMP);
            dj0 += e0 * (float)(j - AMP);
            dj1 += e1 * (float)(j - AMP);
        }
    }
    float inv0 = 1.0f / (l0 * (float)NH);  // /8 = head mean
    float inv1 = 1.0f / (l1 * (float)NH);

    float* o0 = out + ((size_t)b * 2 + 0) * plane + (size_t)h * WW + w;
    float* o1 = out + ((size_t)b * 2 + 1) * plane + (size_t)h * WW + w;
    atomicAdd(o0,     di0 * inv0);
    atomicAdd(o0 + 1, di1 * inv1);
    atomicAdd(o1,     dj0 * inv0);
    atomicAdd(o1 + 1, dj1 * inv1);
}

extern "C" void kernel_launch(void* const* d_in, const int* in_sizes, int n_in,
                              void* d_out, int out_size, void* d_ws, size_t ws_size,
                              hipStream_t stream) {
    const float* q = (const float*)d_in[0];
    const float* k = (const float*)d_in[1];
    float* out = (float*)d_out;

    hipMemsetAsync(out, 0, (size_t)out_size * sizeof(float), stream);

    dim3 grid(WW / TW * (HH / TH), NH, BB);   // (18, 8, 8)
    dim3 block(256);
    hipLaunchKernelGGL(mov_kernel, grid, block, 0, stream, q, k, out);
}

// Round 3
// 187.770 us; speedup vs baseline: 4.1404x; 4.1404x over previous
//
#include <hip/hip_runtime.h>

#define BB 8
#define CC 512
#define NH 8
#define HD 64
#define HH 96
#define WW 96
#define AMP 3
#define KS 7
#define TH 8
#define TW 32
#define HALO_H (TH + 2*AMP)          // 14
#define NGRP 10                      // 10 x float4 = 40 staged cols, x0 = w0-4
#define LDSW 41                      // odd stride -> <=2-way (free) bank aliasing
#define DCH 4                        // d-planes per chunk
#define NCHUNK (HD / DCH)            // 16
#define PLANE (HH * WW)              // 9216
#define NPLANE (NH * PLANE)          // stride between d-planes: 73728
#define NTOT (BB * CC * PLANE)       // 37748736
#define TASKS (DCH * HALO_H * NGRP)  // 560
#define NTHR 128
#define MAXS ((TASKS + NTHR - 1) / NTHR)  // 5

typedef float f4 __attribute__((ext_vector_type(4)));
typedef float f4u __attribute__((ext_vector_type(4), aligned(4)));

__global__ __launch_bounds__(NTHR, 3) void mov_kernel(const float* __restrict__ q,
                                                      const float* __restrict__ k,
                                                      float* __restrict__ out) {
    const int tid = threadIdx.x;       // 0..127
    const int tx  = tid & 15;          // 0..15 (w pixel-pairs)
    const int ty  = tid >> 4;          // 0..7  (h rows)
    const int tw_i = blockIdx.x % (WW / TW);   // 0..2
    const int th_i = blockIdx.x / (WW / TW);   // 0..11
    const int n = blockIdx.y;
    const int b = blockIdx.z;
    const int h0 = th_i * TH;
    const int w0 = tw_i * TW;
    const int h = h0 + ty;
    const int w = w0 + 2 * tx;

    __shared__ float lk[2][DCH][HALO_H][LDSW];

    // ---- precompute fixed staging tasks (no div/branch in the hot loop) ----
    int s_dd[MAXS], s_go[MAXS], s_lo[MAXS];
    bool s_v[MAXS];
#pragma unroll
    for (int s = 0; s < MAXS; ++s) {
        int id = tid + s * NTHR;
        s_v[s] = (id < TASKS);
        int id2 = s_v[s] ? id : 0;
        int dd  = id2 / (HALO_H * NGRP);
        int rem = id2 % (HALO_H * NGRP);
        int r = rem / NGRP;
        int g = rem % NGRP;
        int y = h0 + r - AMP;
        y = min(max(y, 0), HH - 1);          // clamped row; garbage cols masked later
        s_dd[s] = dd;
        s_go[s] = y * WW + (w0 - 4 + 4 * g); // may be <0 at left edge; clamped below
        s_lo[s] = (dd * HALO_H + r) * LDSW + 4 * g;
    }

    const int kbase = (b * CC + n) * PLANE;
    const int qoff  = kbase + h * WW + w;

    float acc0[KS * KS], acc1[KS * KS];
#pragma unroll
    for (int o = 0; o < KS * KS; ++o) { acc0[o] = 0.f; acc1[o] = 0.f; }

    const float scale = 0.125f;   // 64^-0.5

    auto STAGE = [&](int buf, int c) {
        const int pb = kbase + c * DCH * NPLANE;
        float* lb = &lk[buf][0][0][0];
#pragma unroll
        for (int s = 0; s < MAXS; ++s) {
            if (s_v[s]) {
                int idx = pb + s_dd[s] * NPLANE + s_go[s];
                idx = min(max(idx, 0), NTOT - 4);   // stays 16B-aligned
                f4 v = *(const f4*)(k + idx);
                *(f4u*)(lb + s_lo[s]) = v;
            }
        }
    };

    auto COMPUTE = [&](int buf, int c) {
#pragma unroll
        for (int dd = 0; dd < DCH; ++dd) {
            const float* qp = q + qoff + (c * DCH + dd) * NPLANE;
            float q0 = qp[0] * scale;
            float q1 = qp[1] * scale;
#pragma unroll
            for (int i = 0; i < KS; ++i) {
                const float* row = &lk[buf][dd][ty + i][2 * tx + 1];
                float kv[8];
#pragma unroll
                for (int t = 0; t < 8; ++t) kv[t] = row[t];
#pragma unroll
                for (int j = 0; j < KS; ++j) {
                    acc0[i * KS + j] = fmaf(q0, kv[j],     acc0[i * KS + j]);
                    acc1[i * KS + j] = fmaf(q1, kv[j + 1], acc1[i * KS + j]);
                }
            }
        }
    };

    // ---- 2-phase pipeline: stage(c+1) overlaps compute(c), 1 barrier/chunk ----
    STAGE(0, 0);
    __syncthreads();
    for (int c = 0; c < NCHUNK; ++c) {
        if (c + 1 < NCHUNK) STAGE((c + 1) & 1, c + 1);
        COMPUTE(c & 1, c);
        __syncthreads();
    }

    // ---- mask invalid offsets (exactly the out-of-image ones) ----
#pragma unroll
    for (int i = 0; i < KS; ++i) {
        bool vi = ((unsigned)(h + i - AMP) < HH);
#pragma unroll
        for (int j = 0; j < KS; ++j) {
            bool v0 = vi && ((unsigned)(w + j - AMP) < WW);
            bool v1 = vi && ((unsigned)(w + 1 + j - AMP) < WW);
            if (!v0) acc0[i * KS + j] = -1e30f;
            if (!v1) acc1[i * KS + j] = -1e30f;
        }
    }

    // ---- softmax over 49 offsets + expectation of (di, dj) ----
    float m0 = -1e30f, m1 = -1e30f;
#pragma unroll
    for (int o = 0; o < KS * KS; ++o) {
        m0 = fmaxf(m0, acc0[o]);
        m1 = fmaxf(m1, acc1[o]);
    }
    float l0 = 0.f, di0 = 0.f, dj0 = 0.f;
    float l1 = 0.f, di1 = 0.f, dj1 = 0.f;
#pragma unroll
    for (int i = 0; i < KS; ++i) {
#pragma unroll
        for (int j = 0; j < KS; ++j) {
            float e0 = __expf(acc0[i * KS + j] - m0);
            float e1 = __expf(acc1[i * KS + j] - m1);
            l0 += e0; l1 += e1;
            di0 += e0 * (float)(i - AMP);
            di1 += e1 * (float)(i - AMP);
            dj0 += e0 * (float)(j - AMP);
            dj1 += e1 * (float)(j - AMP);
        }
    }
    float inv0 = 1.0f / (l0 * (float)NH);   // /8 = head mean
    float inv1 = 1.0f / (l1 * (float)NH);

    float* o0 = out + ((size_t)b * 2 + 0) * PLANE + h * WW + w;
    float* o1 = out + ((size_t)b * 2 + 1) * PLANE + h * WW + w;
    atomicAdd(o0,     di0 * inv0);
    atomicAdd(o0 + 1, di1 * inv1);
    atomicAdd(o1,     dj0 * inv0);
    atomicAdd(o1 + 1, dj1 * inv1);
}

extern "C" void kernel_launch(void* const* d_in, const int* in_sizes, int n_in,
                              void* d_out, int out_size, void* d_ws, size_t ws_size,
                              hipStream_t stream) {
    const float* q = (const float*)d_in[0];
    const float* k = (const float*)d_in[1];
    float* out = (float*)d_out;

    hipMemsetAsync(out, 0, (size_t)out_size * sizeof(float), stream);

    dim3 grid((HH / TH) * (WW / TW), NH, BB);   // (36, 8, 8) = 2304 blocks
    dim3 block(NTHR);
    hipLaunchKernelGGL(mov_kernel, grid, block, 0, stream, q, k, out);
}

// Round 4
// 91.675 us; speedup vs baseline: 8.4804x; 2.0482x over previous
//
#include <hip/hip_runtime.h>

#define BB 8
#define CC 512
#define NH 8
#define HD 64
#define HH 96
#define WW 96
#define AMP 3
#define KS 7
#define TH 16
#define TW 32
#define NTHR 256
#define HALO_H (TH + 2*AMP)          // 22
#define NGRP 10                      // 10 x 4 cols = 40 staged cols (x0 = w0-4)
#define LDSW 41                      // odd dword stride -> 2-way (free) bank alias
#define NPAIR 2                      // d-pairs per chunk (= 4 planes)
#define NCHUNK 16                    // 64 planes / 4
#define PLANE (HH * WW)              // 9216
#define NPLANE (NH * PLANE)          // 73728
#define NTOT (BB * CC * PLANE)
#define TASKS (NPAIR * HALO_H * NGRP) // 440
#define MAXS 2
#define LKHALF (NPAIR * HALO_H * LDSW) // 1804 h2 per buffer

typedef decltype(__builtin_amdgcn_cvt_pkrtz(0.f, 0.f)) h2;
typedef float f4 __attribute__((ext_vector_type(4)));

__device__ __forceinline__ float dot2f(h2 a, h2 b, float c) {
#if __has_builtin(__builtin_amdgcn_fdot2)
    return __builtin_amdgcn_fdot2(a, b, c, false);
#else
    return c + (float)a[0] * (float)b[0] + (float)a[1] * (float)b[1];
#endif
}

__device__ __forceinline__ void barrier_nb() {
    // lgkmcnt(0) only: LDS writes visible; global loads stay in flight (no vmcnt drain)
    asm volatile("s_waitcnt lgkmcnt(0)" ::: "memory");
    __builtin_amdgcn_s_barrier();
    asm volatile("" ::: "memory");
}

__global__ __launch_bounds__(NTHR)
__attribute__((amdgpu_waves_per_eu(2, 3)))
void mov_kernel(const float* __restrict__ q, const float* __restrict__ k,
                float* __restrict__ out) {
    const int tid = threadIdx.x;
    const int tx  = tid & 15;          // 16 pixel-pairs wide
    const int ty  = tid >> 4;          // 16 rows
    // XCD-aware decode: all 18 tiles of one (b, head) slice share one XCD (bid%8)
    const int bid  = blockIdx.x;       // 0..1151
    const int n    = bid & 7;
    const int t2   = bid >> 3;         // 0..143
    const int b    = t2 / 18;
    const int tile = t2 - b * 18;
    const int th_i = tile / 3;         // 0..5
    const int tw_i = tile - th_i * 3;  // 0..2
    const int h0 = th_i * TH, w0 = tw_i * TW;
    const int h = h0 + ty, w = w0 + 2 * tx;

    __shared__ h2 lk[2 * LKHALF];

    // ---- fixed staging task map (2 tasks/thread, branch-free hot loop) ----
    int s_gpo[MAXS], s_lo[MAXS];
    bool s_v[MAXS];
#pragma unroll
    for (int s = 0; s < MAXS; ++s) {
        int id = tid + s * NTHR;
        s_v[s] = (id < TASKS);
        int id2 = s_v[s] ? id : 0;
        int p   = id2 / (HALO_H * NGRP);
        int rem = id2 - p * (HALO_H * NGRP);
        int r   = rem / NGRP;
        int g   = rem - r * NGRP;
        int y   = min(max(h0 + r - AMP, 0), HH - 1);   // clamped row; masked later
        s_gpo[s] = 2 * p * NPLANE + y * WW + (w0 - 4 + 4 * g);
        s_lo[s]  = (p * HALO_H + r) * LDSW + 4 * g;
    }

    const int kbase = (b * CC + n) * PLANE;
    const int qoff  = kbase + h * WW + w;
    const float scale = 0.125f;

    float acc0[KS * KS], acc1[KS * KS];
#pragma unroll
    for (int o = 0; o < KS * KS; ++o) { acc0[o] = 0.f; acc1[o] = 0.f; }

    f4 ska[MAXS], skb[MAXS];     // staged k: plane 2p / 2p+1
    float2 qv[4];                // this chunk's 4 q planes (2 pixels each)

    auto LOADK = [&](int c) {
#pragma unroll
        for (int s = 0; s < MAXS; ++s) {
            if (s_v[s]) {
                int base = kbase + c * 4 * NPLANE + s_gpo[s];
                int iA = min(max(base, 0), NTOT - 4);
                int iB = min(max(base + NPLANE, 0), NTOT - 4);
                ska[s] = *(const f4*)(k + iA);
                skb[s] = *(const f4*)(k + iB);
            }
        }
    };
    auto LOADQ = [&](int c) {
#pragma unroll
        for (int d = 0; d < 4; ++d)
            qv[d] = *(const float2*)(q + qoff + (c * 4 + d) * NPLANE);
    };
    auto WRITEK = [&](int buf) {
#pragma unroll
        for (int s = 0; s < MAXS; ++s) {
            if (s_v[s]) {
                h2* dst = &lk[buf * LKHALF + s_lo[s]];
#pragma unroll
                for (int u = 0; u < 4; ++u)
                    dst[u] = __builtin_amdgcn_cvt_pkrtz(ska[s][u], skb[s][u]);
            }
        }
    };

    LOADK(0);
    LOADQ(0);
    for (int c = 0; c < NCHUNK; ++c) {
        const int buf = c & 1;
        WRITEK(buf);                       // waits vmcnt on this chunk's k loads
        if (c + 1 < NCHUNK) LOADK(c + 1);  // reuse regs; in flight across barrier
        h2 qq0[NPAIR], qq1[NPAIR];
#pragma unroll
        for (int p = 0; p < NPAIR; ++p) {  // pack q pairs (d-major)
            qq0[p] = __builtin_amdgcn_cvt_pkrtz(qv[2 * p].x * scale, qv[2 * p + 1].x * scale);
            qq1[p] = __builtin_amdgcn_cvt_pkrtz(qv[2 * p].y * scale, qv[2 * p + 1].y * scale);
        }
        if (c + 1 < NCHUNK) LOADQ(c + 1);
        barrier_nb();
        // ---- 49-offset dot accumulation via v_dot2 (2 planes / instr) ----
#pragma unroll
        for (int p = 0; p < NPAIR; ++p) {
#pragma unroll
            for (int i = 0; i < KS; ++i) {
                const int rb = buf * LKHALF + (p * HALO_H + ty + i) * LDSW + 2 * tx + 1;
                h2 kv[8];
#pragma unroll
                for (int t = 0; t < 8; ++t) kv[t] = lk[rb + t];
#pragma unroll
                for (int j = 0; j < KS; ++j) {
                    acc0[i * KS + j] = dot2f(qq0[p], kv[j],     acc0[i * KS + j]);
                    acc1[i * KS + j] = dot2f(qq1[p], kv[j + 1], acc1[i * KS + j]);
                }
            }
        }
        barrier_nb();   // readers done before next overwrite of this buffer
    }

    // ---- mask invalid offsets (reference: -1000 -> exp == 0) ----
#pragma unroll
    for (int i = 0; i < KS; ++i) {
        bool vi = ((unsigned)(h + i - AMP) < HH);
#pragma unroll
        for (int j = 0; j < KS; ++j) {
            bool v0 = vi && ((unsigned)(w + j - AMP) < WW);
            bool v1 = vi && ((unsigned)(w + 1 + j - AMP) < WW);
            if (!v0) acc0[i * KS + j] = -1e30f;
            if (!v1) acc1[i * KS + j] = -1e30f;
        }
    }

    // ---- softmax over 49 offsets + expectation of (di, dj) ----
    float m0 = -1e30f, m1 = -1e30f;
#pragma unroll
    for (int o = 0; o < KS * KS; ++o) {
        m0 = fmaxf(m0, acc0[o]);
        m1 = fmaxf(m1, acc1[o]);
    }
    float l0 = 0.f, di0 = 0.f, dj0 = 0.f;
    float l1 = 0.f, di1 = 0.f, dj1 = 0.f;
#pragma unroll
    for (int i = 0; i < KS; ++i) {
#pragma unroll
        for (int j = 0; j < KS; ++j) {
            float e0 = __expf(acc0[i * KS + j] - m0);
            float e1 = __expf(acc1[i * KS + j] - m1);
            l0 += e0; l1 += e1;
            di0 += e0 * (float)(i - AMP);
            di1 += e1 * (float)(i - AMP);
            dj0 += e0 * (float)(j - AMP);
            dj1 += e1 * (float)(j - AMP);
        }
    }
    float inv0 = 1.0f / (l0 * (float)NH);
    float inv1 = 1.0f / (l1 * (float)NH);

    float* o0 = out + ((size_t)b * 2 + 0) * PLANE + h * WW + w;
    float* o1 = out + ((size_t)b * 2 + 1) * PLANE + h * WW + w;
    atomicAdd(o0,     di0 * inv0);
    atomicAdd(o0 + 1, di1 * inv1);
    atomicAdd(o1,     dj0 * inv0);
    atomicAdd(o1 + 1, dj1 * inv1);
}

extern "C" void kernel_launch(void* const* d_in, const int* in_sizes, int n_in,
                              void* d_out, int out_size, void* d_ws, size_t ws_size,
                              hipStream_t stream) {
    const float* q = (const float*)d_in[0];
    const float* k = (const float*)d_in[1];
    float* out = (float*)d_out;

    hipMemsetAsync(out, 0, (size_t)out_size * sizeof(float), stream);

    dim3 grid(BB * NH * (HH / TH) * (WW / TW));   // 1152, XCD-decoded in-kernel
    dim3 block(NTHR);
    hipLaunchKernelGGL(mov_kernel, grid, block, 0, stream, q, k, out);
}